// Round 8
// baseline (167.379 us; speedup 1.0000x reference)
//
#include <hip/hip_runtime.h>

#define K1N 10
#define K2N 10
#define MMN 50

typedef __attribute__((ext_vector_type(8))) short short8;
typedef __attribute__((ext_vector_type(4))) float f32x4;

__device__ __forceinline__ float fast_tanh(float x) {
  x = fminf(fmaxf(x, -15.f), 15.f);
  float e2 = __expf(2.f * x);
  return (e2 - 1.f) * __builtin_amdgcn_rcpf(e2 + 1.f);
}

// reference's _avg_on_real_neighbor weight (exact f32 semantics)
__device__ __forceinline__ float nb_w(float cnt) {
  float w = 1.0f / (cnt + 1e-8f);
  return (w >= 1e8f) ? 0.f : w;
}

// f32 -> bf16 RNE as raw ushort; exact bf16 -> f32
__device__ __forceinline__ unsigned short f2bf(float x) {
  unsigned u = __builtin_bit_cast(unsigned, x);
  return (unsigned short)((u + 0x7FFFu + ((u >> 16) & 1u)) >> 16);
}
__device__ __forceinline__ float bf2f(unsigned short s) {
  return __builtin_bit_cast(float, ((unsigned)s) << 16);
}

__device__ __forceinline__ void fma4(float& y, float4 w, float4 x) {
  y = fmaf(w.x, x.x, y);
  y = fmaf(w.y, x.y, y);
  y = fmaf(w.z, x.z, y);
  y = fmaf(w.w, x.w, y);
}

// stage 64x64 f32 into LDS, XOR-swizzled float4 chunks (final kernel)
__device__ __forceinline__ void stage_w(const float* __restrict__ W, float* lds, int tid) {
  const float4* src = reinterpret_cast<const float4*>(W);
  float4* dst = reinterpret_cast<float4*>(lds);
#pragma unroll
  for (int i = 0; i < 4; ++i) {
    int c = tid + i * 256;
    int e = c >> 4, q = c & 15;
    dst[(e << 4) | (q ^ (e & 7))] = src[c];
  }
}

#define MFMA16(A, B, C) __builtin_amdgcn_mfma_f32_16x16x32_bf16(A, B, C, 0, 0, 0)

// one phase-1 k-chunk: 16 MFMA rows, row u = bi*4+kq (bi=u>>2, kq=u&3), kq<KQ valid.
// Wave-wide coalesced gathers (lane = dim), X via per-wave swizzled LDS planes.
// X planes: {t1-hi, t1-lo, t2-hi} (t2-lo dropped: ~1e-6 rms contribution).
template <int KQ>
__device__ __forceinline__ void p1_step(
    int kbase, int b0w, int lane, int g, int r15,
    const int* __restrict__ dsd1, const int* __restrict__ dsd2,
    const float* __restrict__ symp, const float* __restrict__ dise,
    const unsigned short* __restrict__ Wl0, const unsigned short* __restrict__ Wl1,
    unsigned short* xw, const short8 (&Bh)[2][4][2],
    float (&s1sum)[4], float& c1f) {
  // ---- gather + 3-plane X writes (single pass) ----
#pragma unroll
  for (int u = 0; u < 16; ++u) {
    if ((u & 3) >= KQ) continue;
    const int b = b0w + (u >> 2);
    const int k = kbase + (u & 3);
    const int sidx = dsd1[b * K1N + k];         // wave-uniform -> s_load
    float es = symp[(sidx << 6) | lane];        // coalesced full row
    const int* dp = dsd2 + (b * K1N + k) * K2N; // wave-uniform -> s_load
    float acc = 0.f;
    int c2 = 0;
#pragma unroll
    for (int j = 0; j < K2N; ++j) {
      int dj = dp[j];
      c2 += (dj != 0);
      acc += dise[(dj << 6) | lane];            // dise row 0 is exactly zero
    }
    float w2 = (c2 == 0) ? 0.f : __builtin_amdgcn_rcpf((float)c2 + 1e-8f);
    float ad = acc * w2;
    float t1 = es + ad, t2 = es * ad;
    c1f += ((g == (u >> 2)) && (sidx != 0)) ? 1.f : 0.f;
    const int off = u * 64 + (((lane >> 3) ^ (u & 7)) << 3) + (lane & 7);
    unsigned short hh = f2bf(t1);
    xw[off] = hh;
    xw[1024 + off] = f2bf(t1 - bf2f(hh));
    xw[2048 + off] = f2bf(t2);
  }
  asm volatile("s_waitcnt lgkmcnt(0)" ::: "memory");  // own-wave X writes visible

  // ---- MFMA: Y = X1*W21^T + X2*W22^T, bf16 split; hi from regs, lo from LDS ----
  f32x4 acc4[4];
#pragma unroll
  for (int nt = 0; nt < 4; ++nt) acc4[nt] = (f32x4){0.f, 0.f, 0.f, 0.f};
#pragma unroll
  for (int ks = 0; ks < 2; ++ks) {
    const int aoff = r15 * 64 + (((4 * ks + g) ^ (r15 & 7)) << 3);
    short8 a1h = *(const short8*)(xw + aoff);
    short8 a1l = *(const short8*)(xw + 1024 + aoff);
    short8 a2h = *(const short8*)(xw + 2048 + aoff);
#pragma unroll
    for (int nt = 0; nt < 4; ++nt) {
      const int wb = (nt * 16 + r15) * 64 + (((4 * ks + g) ^ (r15 & 7)) << 3);
      short8 w21l = *(const short8*)(Wl0 + wb);
      short8 w22l = *(const short8*)(Wl1 + wb);
      acc4[nt] = MFMA16(a1h, Bh[0][nt][ks], acc4[nt]);
      acc4[nt] = MFMA16(a1l, Bh[0][nt][ks], acc4[nt]);
      acc4[nt] = MFMA16(a1h, w21l, acc4[nt]);
      acc4[nt] = MFMA16(a2h, Bh[1][nt][ks], acc4[nt]);
      acc4[nt] = MFMA16(a2h, w22l, acc4[nt]);
    }
  }
  // ---- epilogue: rows 4g+rr belong to elem g (kq=rr); tanh + l2norm ----
#pragma unroll
  for (int rr = 0; rr < KQ; ++rr) {
    float ta[4], ss = 0.f;
#pragma unroll
    for (int nt = 0; nt < 4; ++nt) {
      ta[nt] = fast_tanh(acc4[nt][rr]);
      ss = fmaf(ta[nt], ta[nt], ss);
    }
    ss += __shfl_xor(ss, 1, 64); ss += __shfl_xor(ss, 2, 64);
    ss += __shfl_xor(ss, 4, 64); ss += __shfl_xor(ss, 8, 64);
    float inv = __builtin_amdgcn_rcpf(fmaxf(sqrtf(ss), 1e-12f));
#pragma unroll
    for (int nt = 0; nt < 4; ++nt) s1sum[nt] = fmaf(ta[nt], inv, s1sum[nt]);
  }
}

// ============ phase 1: 4 waves/block, wave = 4 elems, 40 KB LDS = exactly 4 blocks/CU ============
__global__ __launch_bounds__(256, 4) void hgnn_phase1(
    const int* __restrict__ dsd1, const int* __restrict__ dsd2,
    const float* __restrict__ symp, const float* __restrict__ dise,
    const float* __restrict__ W21, const float* __restrict__ W22,
    float* __restrict__ s1avg) {
  __shared__ unsigned short Wl[2][4096];     // {w21lo, w22lo} swizzled bf16 planes (16 KB)
  __shared__ unsigned short Xs[4][3][1024];  // per-wave {t1h,t1l,t2h} (24 KB)
  const int tid = threadIdx.x;
  const int lane = tid & 63;
  const int wv = __builtin_amdgcn_readfirstlane(tid >> 6);
  const int g = lane >> 4, r15 = lane & 15;

  // stage W lo planes: 1024 16B-chunks, 4/thread
#pragma unroll
  for (int i = 0; i < 4; ++i) {
    int c = tid + (i << 8);
    int pl = c >> 9, rc = c & 511;
    int row = rc >> 3, ch = rc & 7;
    const float* src = (pl ? W22 : W21) + row * 64 + ch * 8;
    short8 v;
#pragma unroll
    for (int j = 0; j < 8; ++j) {
      float w = src[j];
      v[j] = (short)f2bf(w - bf2f(f2bf(w)));
    }
    *reinterpret_cast<short8*>(&Wl[pl][row * 64 + ((ch ^ (row & 7)) << 3)]) = v;
  }
  // W21/W22 hi B-frags into 64 VGPRs
  short8 Bh[2][4][2];
#pragma unroll
  for (int mat = 0; mat < 2; ++mat) {
    const float* Wm = mat ? W22 : W21;
#pragma unroll
    for (int nt = 0; nt < 4; ++nt)
#pragma unroll
      for (int ks = 0; ks < 2; ++ks) {
        const float4* p = reinterpret_cast<const float4*>(Wm + (nt * 16 + r15) * 64 + ks * 32 + g * 8);
        float4 va = p[0], vb = p[1];
        short8 h;
        h[0] = (short)f2bf(va.x); h[1] = (short)f2bf(va.y);
        h[2] = (short)f2bf(va.z); h[3] = (short)f2bf(va.w);
        h[4] = (short)f2bf(vb.x); h[5] = (short)f2bf(vb.y);
        h[6] = (short)f2bf(vb.z); h[7] = (short)f2bf(vb.w);
        Bh[mat][nt][ks] = h;
      }
  }
  __syncthreads();

  const int b0w = blockIdx.x * 16 + wv * 4;
  unsigned short* xw = &Xs[wv][0][0];
  float s1sum[4] = {0.f, 0.f, 0.f, 0.f};
  float c1f = 0.f;

  p1_step<4>(0, b0w, lane, g, r15, dsd1, dsd2, symp, dise, Wl[0], Wl[1], xw, Bh, s1sum, c1f);
  p1_step<4>(4, b0w, lane, g, r15, dsd1, dsd2, symp, dise, Wl[0], Wl[1], xw, Bh, s1sum, c1f);
  p1_step<2>(8, b0w, lane, g, r15, dsd1, dsd2, symp, dise, Wl[0], Wl[1], xw, Bh, s1sum, c1f);

  // c1f is uniform within each g-group; elem = b0w + g, cols d = nt*16 + r15
  float w1 = nb_w(c1f);
  float* dst = s1avg + (size_t)(b0w + g) * 64 + r15;
#pragma unroll
  for (int nt = 0; nt < 4; ++nt) dst[nt * 16] = s1sum[nt] * w1;
}

// ============ usu gather-average: quad-row loads (4 symp rows per instruction) ============
// wave = 4 elems; per elem: preload 50 idx into lanes, 13 quad-row loads, 1 cross-group reduce
__global__ __launch_bounds__(256, 8) void hgnn_usu_avg(
    const int* __restrict__ usu1, const float* __restrict__ symp,
    float* __restrict__ mu) {
  const int tid = threadIdx.x;
  const int lane = tid & 63;
  const int wv = __builtin_amdgcn_readfirstlane(tid >> 6);
  const int grp = lane >> 4;
  const int d4 = (lane & 15) << 2;  // this lane's 4-dim slice
  const int b0 = blockIdx.x * 16 + wv * 4;

#pragma unroll
  for (int e = 0; e < 4; ++e) {
    const int b = b0 + e;
    int ui = 0;
    if (lane < MMN) ui = usu1[b * MMN + lane];
    float cnt = (float)__popcll(__ballot(ui != 0));
    f32x4 su = {0.f, 0.f, 0.f, 0.f};
    // 12 quad-iters cover m=0..47 (group g takes m+g); tail covers 48,49
#pragma unroll
    for (int m = 0; m < 48; m += 4) {
      int idx = __shfl(ui, m + grp, 64);
      su += *(const f32x4*)(symp + (idx << 6) + d4);  // symp row 0 is exactly zero
    }
    {
      int idx = __shfl(ui, 48 + grp, 64);
      if (grp < 2) su += *(const f32x4*)(symp + (idx << 6) + d4);
    }
    // reduce the 4 lane-groups (each holds a partial over its neighbor subset)
#pragma unroll
    for (int c = 0; c < 4; ++c) {
      su[c] += __shfl_xor(su[c], 16, 64);
      su[c] += __shfl_xor(su[c], 32, 64);
    }
    float w = nb_w(cnt);
    if (lane < 16) {
      f32x4 r = su * w;
      *reinterpret_cast<f32x4*>(mu + (size_t)b * 64 + d4) = r;
    }
  }
}

// ================= final: label gather + 3 matvecs + dot (proven round-3 kernel) =================
__global__ __launch_bounds__(256, 2) void hgnn_final(
    const int* __restrict__ label, const float* __restrict__ dise,
    const float* __restrict__ W11, const float* __restrict__ W12,
    const float* __restrict__ Wu,
    const float* __restrict__ s1avg, const float* __restrict__ mu,
    float* __restrict__ out) {
  __shared__ float lw[3][4096];
  __shared__ float xb[4][4][3][64];
  const int tid = threadIdx.x;
  const int lane = tid & 63;
  const int wv = __builtin_amdgcn_readfirstlane(tid >> 6);
  stage_w(W11, lw[0], tid);
  stage_w(W12, lw[1], tid);
  stage_w(Wu, lw[2], tid);
  __syncthreads();

  const int b0 = blockIdx.x * 16 + wv * 4;
#pragma unroll
  for (int bi = 0; bi < 4; ++bi) {
    const int b = b0 + bi;
    float s1 = s1avg[(size_t)b * 64 + lane];
    float mv = mu[(size_t)b * 64 + lane];
    int lb = label[b];
    float t = dise[(lb << 6) | lane];
    xb[wv][bi][0][lane] = s1 + t;
    xb[wv][bi][1][lane] = s1 * t;
    xb[wv][bi][2][lane] = mv;
  }
  asm volatile("s_waitcnt lgkmcnt(0)" ::: "memory");

  float y1[4] = {0.f, 0.f, 0.f, 0.f};
  float y2[4] = {0.f, 0.f, 0.f, 0.f};
  const int swz = lane & 7;
#pragma unroll 4
  for (int q = 0; q < 16; ++q) {
    float4 wa = reinterpret_cast<float4*>(lw[0])[(lane << 4) | (q ^ swz)];
    float4 wb = reinterpret_cast<float4*>(lw[1])[(lane << 4) | (q ^ swz)];
    float4 wc = reinterpret_cast<float4*>(lw[2])[(lane << 4) | (q ^ swz)];
#pragma unroll
    for (int bi = 0; bi < 4; ++bi) {
      float4 xv1 = *reinterpret_cast<const float4*>(&xb[wv][bi][0][q << 2]);
      float4 xv2 = *reinterpret_cast<const float4*>(&xb[wv][bi][1][q << 2]);
      float4 xv3 = *reinterpret_cast<const float4*>(&xb[wv][bi][2][q << 2]);
      fma4(y1[bi], wa, xv1);
      fma4(y1[bi], wb, xv2);
      fma4(y2[bi], wc, xv3);
    }
  }
#pragma unroll
  for (int bi = 0; bi < 4; ++bi) {
    float ed = fast_tanh(y1[bi]);
    float eu = fast_tanh(y2[bi]);
    float p = ed * eu;
#pragma unroll
    for (int off = 32; off; off >>= 1) p += __shfl_xor(p, off, 64);
    if (lane == 0) out[b0 + bi] = p;
  }
}

extern "C" void kernel_launch(void* const* d_in, const int* in_sizes, int n_in,
                              void* d_out, int out_size, void* d_ws, size_t ws_size,
                              hipStream_t stream) {
  const int* dsd1 = (const int*)d_in[0];
  const int* dsd2 = (const int*)d_in[1];
  const int* usu1 = (const int*)d_in[2];
  const int* label = (const int*)d_in[3];
  const float* symp = (const float*)d_in[4];
  const float* dise = (const float*)d_in[5];
  const float* Wu = (const float*)d_in[6];
  const float* W21 = (const float*)d_in[7];
  const float* W22 = (const float*)d_in[8];
  const float* W11 = (const float*)d_in[9];
  const float* W12 = (const float*)d_in[10];
  float* out = (float*)d_out;

  const int B = in_sizes[3];
  float* s1 = (float*)d_ws;         // B*64 f32 = 4 MB
  float* mu = s1 + (size_t)B * 64;  // B*64 f32 = 4 MB

  hipLaunchKernelGGL(hgnn_phase1, dim3(B / 16), dim3(256), 0, stream,
                     dsd1, dsd2, symp, dise, W21, W22, s1);
  hipLaunchKernelGGL(hgnn_usu_avg, dim3(B / 16), dim3(256), 0, stream,
                     usu1, symp, mu);
  hipLaunchKernelGGL(hgnn_final, dim3(B / 16), dim3(256), 0, stream,
                     label, dise, W11, W12, Wu, s1, mu, out);
}